// Round 17
// baseline (188.448 us; speedup 1.0000x reference)
//
#include <hip/hip_runtime.h>
#include <hip/hip_bf16.h>

#define B_ 4
#define D_ 64
#define N_ 16
#define HW_ 4096

#define LDSA 72
#define LDSB 66
#define EXPU 68   // EX pitch in u16 (136 B rows)

// workspace offsets (bytes)
#define OFF_D2    0u
#define OFF_ATAB  8192u
#define OFF_MEAN  12288u
#define OFF_RSTD  12352u
#define OFF_W9    16384u
#define OFF_UNT   131072u
#define OFF_DELTA 2228224u
#define OFF_BVAL  6422528u
#define OFF_CVAL  7471104u
#define OFF_YBUF  8519680u
#define OFF_YBUF2 12713984u   // second y partial (4 MB after YBUF)

typedef __bf16 v8bf __attribute__((ext_vector_type(8)));
typedef float  v4f  __attribute__((ext_vector_type(4)));

__device__ __forceinline__ unsigned short f2bf(float f){
  __hip_bfloat16 h = __float2bfloat16(f);
  return *reinterpret_cast<unsigned short*>(&h);
}
__device__ __forceinline__ float bf2f(unsigned int u){
  union{unsigned int i; float f;} c; c.i = (u & 0xffffu)<<16; return c.f;
}
__device__ __forceinline__ v8bf ld8bf(const unsigned short* p){
  union{uint4 u; v8bf v;} c; c.u = *(const uint4*)p; return c.v;
}
// non-temporal float4 store via clang ext-vector type
__device__ __forceinline__ void nt_store4(float4 v, float4* p){
  v4f w = {v.x, v.y, v.z, v.w};
  __builtin_nontemporal_store(w, (v4f*)p);
}

// force a float4 to be materialized in VGPRs at this program point
__device__ __forceinline__ void pin4(const float4& v){
  asm volatile("" :: "v"(v.x), "v"(v.y), "v"(v.z), "v"(v.w));
}

// LDS-only barrier: orders cross-thread LDS, leaves global ops in flight
__device__ __forceinline__ void bar_lgkm(){
  asm volatile("s_waitcnt lgkmcnt(0)" ::: "memory");
  __builtin_amdgcn_s_barrier();
  __builtin_amdgcn_sched_barrier(0);
}

// wave-local LDS publish: wait own LDS ops, no block barrier
__device__ __forceinline__ void wave_lgkm(){
  asm volatile("s_waitcnt lgkmcnt(0)" ::: "memory");
  __builtin_amdgcn_sched_barrier(0);
}

// ---------------- init: spectral-derivative table + A = -exp(logA) ----------
__global__ void k_init(const float* __restrict__ logA,
                       unsigned short* __restrict__ D2w, float* __restrict__ Atab){
  int g = blockIdx.x*256 + threadIdx.x;
  if(g < 4096){
    int r = g>>6, m = g&63;
    int p = (r - m) & 63;
    float s = 0.f;
    for(int k=1;k<32;k++) s += (float)k * sinf(0.09817477042468103f * (float)(k*p));
    D2w[g] = f2bf(-0.0030679615757712823f * s);
  } else if(g < 5120){
    int idx = g - 4096;
    Atab[idx] = -__expf(logA[idx]);
  }
}

// ---------------- repack conv weights to [tap][co(96)][ci(64)] bf16 ---------
__global__ void k_wrepack(const float* __restrict__ wd,
                          const float* __restrict__ wB,
                          const float* __restrict__ wC,
                          unsigned short* __restrict__ W9){
  int idx = blockIdx.x*256 + threadIdx.x;   // 0..6143
  if(idx >= 96*64) return;
  int co = idx>>6, ci = idx&63;
  const float* src;
  if(co < 64)      src = wd + ((size_t)co*64 + ci)*9;
  else if(co < 80) src = wB + ((size_t)(co-64)*64 + ci)*9;
  else             src = wC + ((size_t)(co-80)*64 + ci)*9;
  for(int tap=0; tap<9; tap++)
    W9[((size_t)tap*96 + co)*64 + ci] = f2bf(src[tap]);
}

// ---------------- GroupNorm statistics (16 groups of 65536 elems) -----------
__global__ void k_gnstats(const float* __restrict__ u,
                          float* __restrict__ meanw, float* __restrict__ rstdw){
  int bg = blockIdx.x;                       // 0..15  (b*4+g), group contiguous
  const float* base = u + (size_t)bg*65536;
  int t = threadIdx.x;                       // 0..1023
  float s=0.f, s2=0.f;
  for(int j=0;j<16;j++){
    float4 v = ((const float4*)base)[t + 1024*j];
    s  += v.x+v.y+v.z+v.w;
    s2 += v.x*v.x+v.y*v.y+v.z*v.z+v.w*v.w;
  }
  for(int o=32;o>0;o>>=1){ s += __shfl_down(s,o); s2 += __shfl_down(s2,o); }
  __shared__ float ls[16], ls2[16];
  int wv = t>>6;
  if((t&63)==0){ ls[wv]=s; ls2[wv]=s2; }
  __syncthreads();
  if(t==0){
    float S=0.f,S2=0.f;
    for(int i=0;i<16;i++){ S+=ls[i]; S2+=ls2[i]; }
    float mu = S/65536.f;
    float var = S2/65536.f - mu*mu;
    meanw[bg]=mu; rstdw[bg]=rsqrtf(var+1e-5f);
  }
}

// ---------------- apply GN + transpose to unT[b][pixel][ci] (bf16) ----------
__global__ __launch_bounds__(256) void k_unT(
    const float* __restrict__ u_t,
    const float* __restrict__ meanw, const float* __restrict__ rstdw,
    const float* __restrict__ gamma, const float* __restrict__ beta,
    unsigned short* __restrict__ unT){
  __shared__ unsigned short T[64*LDSA];
  int bid = blockIdx.x;
  int b = bid>>6, h = bid&63;
  int t = threadIdx.x;
  int w = t&63, cg = t>>6;
  #pragma unroll
  for(int i=0;i<16;i++){
    int c = cg*16 + i;
    float x = u_t[(((size_t)b*64 + c)*64 + h)*64 + w];
    int g = c>>4;
    float v = (x - meanw[b*4+g])*rstdw[b*4+g]*gamma[c] + beta[c];
    T[w*LDSA + c] = f2bf(v);
  }
  __syncthreads();
  int w2 = t>>2, cq = t&3;
  uint4 v0 = *(uint4*)&T[w2*LDSA + cq*16];
  uint4 v1 = *(uint4*)&T[w2*LDSA + cq*16 + 8];
  uint4* dst = (uint4*)(unT + ((size_t)b*HW_ + h*64 + w2)*64 + cq*16);
  dst[0] = v0; dst[1] = v1;
}

// ---------------- conv as 9 shifted GEMMs via MFMA --------------------------
__global__ __launch_bounds__(256) void k_conv(
    const unsigned short* __restrict__ unT,
    const unsigned short* __restrict__ W9,
    const float* __restrict__ b_d,
    const float* __restrict__ dtp,
    float* __restrict__ deltaw, float* __restrict__ Bvalw, float* __restrict__ Cvalw){
  int bid = blockIdx.x;
  int b = bid>>6, h = bid&63;
  int t = threadIdx.x;
  int wv = t>>6, l = t&63;
  int lr = l&15, lk = l>>4;
  v4f acc[6];
  #pragma unroll
  for(int i=0;i<6;i++) acc[i] = (v4f){0.f,0.f,0.f,0.f};
  int wpix = wv*16 + lr;
  #pragma unroll
  for(int tap=0; tap<9; tap++){
    int dy = tap/3 - 1, dx = tap - (tap/3)*3 - 1;
    int hh = (h+dy)&63;
    int ww = (wpix+dx)&63;
    const unsigned short* bp = unT + ((size_t)b*HW_ + hh*64 + ww)*64;
    const unsigned short* ap = W9 + (size_t)tap*96*64;
    #pragma unroll
    for(int ks=0; ks<2; ks++){
      int k0 = ks*32 + lk*8;
      v8bf bfrag = ld8bf(bp + k0);
      #pragma unroll
      for(int mt=0; mt<6; mt++){
        v8bf afrag = ld8bf(ap + (mt*16+lr)*64 + k0);
        acc[mt] = __builtin_amdgcn_mfma_f32_16x16x32_bf16(afrag, bfrag, acc[mt], 0,0,0);
      }
    }
  }
  float dt = dtp[0];
  int p = h*64 + wpix;
  #pragma unroll
  for(int mt=0; mt<6; mt++){
    #pragma unroll
    for(int r=0;r<4;r++){
      int co = mt*16 + lk*4 + r;
      float v = acc[mt][r];
      if(co < 64){
        float x = v + b_d[co] + dt;
        float sp = (x > 15.f) ? x : log1pf(__expf(x));
        sp = fminf(fmaxf(sp, 1e-4f), 5.f);
        deltaw[((size_t)b*64 + co)*HW_ + p] = sp;
      } else if(co < 80){
        Bvalw[((size_t)b*16 + (co-64))*HW_ + p] = v;
      } else {
        Cvalw[((size_t)b*16 + (co-80))*HW_ + p] = v;
      }
    }
  }
}

// ---------------- fused spectral-grad + state update ------------------------
// v17 = v16 (wave-local exchange + NT out_s) + nq 4->8 grid split (R7 redux
// under the NT regime). R7's +90MB WRITE inflation was ybuf atomic-line
// thrash: out_s dirty lines churning L2 evicted ybuf lines between atomic
// visits. NT stores removed that churn -> ybuf partials (8MB) stay
// L2-resident. 2048 blocks -> 6 resident/CU (LDS 25.6KB), 1.5x waves for
// latency hiding. Two y-partial buffers keep visits/line/buffer at 4.
__global__ __launch_bounds__(256, 4) void k_main(
    const float* __restrict__ u_t,
    const float* __restrict__ s_prev,
    const unsigned short* __restrict__ D2w,
    const float* __restrict__ Atab,
    const float* __restrict__ deltaw,
    const float* __restrict__ Bvalw,
    const float* __restrict__ Cvalw,
    float* __restrict__ ybuf,
    float* __restrict__ ybuf2,
    float* __restrict__ out_s){
  __shared__ __align__(16) unsigned short Ms66[64*LDSB];   // 8448 B
  __shared__ __align__(16) unsigned short D2s [64*LDSB];   // 8448 B
  __shared__ __align__(16) unsigned short EX  [64*EXPU];   // 8704 B

  int bid = blockIdx.x;                 // bid = nq2*256 + (d*4+b); bid%8==pair%8
  int pair = bid & 255;                 // -> all 8 blocks of a (b,d) share XCD
  int b = pair & 3, d = pair >> 2;
  int nq2 = bid >> 8;                   // 0..7, 2 n each
  int t = threadIdx.x;
  int wv = t>>6, l = t&63;
  int lr = l & 15, lk = l >> 4;
  int r0 = wv*16;
  int gA = wv*256 + l;                  // granule base; granule k = gA + 64k

  size_t bd = (size_t)b*64 + d;
  const size_t PL = (size_t)D_*N_*HW_;
  size_t sbase = (size_t)b*3*PL + (size_t)d*N_*HW_;
  int n0 = nq2*2;

  const float* m0base = s_prev + sbase;
  const float* mxbase = s_prev + sbase + PL;
  const float* mybase = s_prev + sbase + 2*PL;

  // ---- D2 staging (pitch 66) + u/delta block-resident (remapped granules) -
  uint4 d2v0 = ((const uint4*)D2w)[t];
  uint4 d2v1 = ((const uint4*)D2w)[t+256];
  { int r = t>>3, cb = t&7;            *(uint4*)&D2s[r*LDSB + cb*8] = d2v0; }
  { int c2 = t+256; int r = c2>>3, cb = c2&7; *(uint4*)&D2s[r*LDSB + cb*8] = d2v1; }
  const float4* uv4 = (const float4*)(u_t + bd*HW_);
  const float4* dv4 = (const float4*)(deltaw + bd*HW_);
  float4 uq0 = uv4[gA], uq1 = uv4[gA+64], uq2 = uv4[gA+128], uq3 = uv4[gA+192];
  float4 dq0 = dv4[gA], dq1 = dv4[gA+64], dq2 = dv4[gA+128], dq3 = dv4[gA+192];

  float4 yq0 = make_float4(0.f,0.f,0.f,0.f);
  float4 yq1 = yq0, yq2 = yq0, yq3 = yq0;

  for(int ni=0; ni<2; ni++){
    int n = n0 + ni;
    // ---- read burst (top of ni): m0 first, then mx/my (remapped) ----------
    const float4* m0v = (const float4*)(m0base + (size_t)n*HW_);
    float4 pm0 = m0v[gA], pm1 = m0v[gA+64], pm2 = m0v[gA+128], pm3 = m0v[gA+192];
    const float4* mxv = (const float4*)(mxbase + (size_t)n*HW_);
    const float4* myv = (const float4*)(mybase + (size_t)n*HW_);
    float4 sx0 = mxv[gA], sx1 = mxv[gA+64], sx2 = mxv[gA+128], sx3 = mxv[gA+192];
    float4 sy0 = myv[gA], sy1 = myv[gA+64], sy2 = myv[gA+128], sy3 = myv[gA+192];

    // ---- stage m0 (fp32->bf16) into Ms66 (single copy) --------------------
    // granule k: row = r0 + 4k + lk, col quad = lr
    #pragma unroll
    for(int j=0;j<4;j++){
      float4 v = (j==0)?pm0:(j==1)?pm1:(j==2)?pm2:pm3;
      int row = r0 + 4*j + lk;
      unsigned int lo = (unsigned int)f2bf(v.x) | ((unsigned int)f2bf(v.y)<<16);
      unsigned int hi = (unsigned int)f2bf(v.z) | ((unsigned int)f2bf(v.w)<<16);
      unsigned int* d66 = (unsigned int*)&Ms66[row*LDSB + lr*4];
      d66[0]=lo; d66[1]=hi;
    }
    bar_lgkm();                        // publish M; mx/my keep flying

    // ---- MFMA phase: gx -> EX immediately; gy held in regs ----------------
    v4f gya[4];
    #pragma unroll
    for(int ct=0; ct<4; ct++){
      v4f gx = {0.f,0.f,0.f,0.f}, gy = {0.f,0.f,0.f,0.f};
      #pragma unroll
      for(int ks=0; ks<2; ks++){
        int k0 = ks*32 + lk*8;
        // Gx^T = D2 * M^T : row-contiguous reads from pitch-66
        v8bf a_gx = ld8bf(&D2s[(ct*16+lr)*LDSB + k0]);
        v8bf b_gx = ld8bf(&Ms66[(r0+lr)*LDSB + k0]);
        gx = __builtin_amdgcn_mfma_f32_16x16x32_bf16(a_gx, b_gx, gx, 0,0,0);
        // Gy^T = M^T * D2^T : conflict-free column gather (66-pitch design)
        union { unsigned short s[8]; v8bf v; } ag;
        #pragma unroll
        for(int i=0;i<8;i++) ag.s[i] = Ms66[(k0+i)*LDSB + ct*16 + lr];
        v8bf b_gy = ld8bf(&D2s[(r0+lr)*LDSB + k0]);
        gy = __builtin_amdgcn_mfma_f32_16x16x32_bf16(ag.v, b_gy, gy, 0,0,0);
      }
      // gx fragment (row r0+lr, cols ct*16+lk*4+{0..3}) -> bf16-packed EX
      int eo = (r0+lr)*EXPU + (ct*4+lk)*4;
      unsigned int x0 = (unsigned int)f2bf(gx[0]) | ((unsigned int)f2bf(gx[1])<<16);
      unsigned int x1 = (unsigned int)f2bf(gx[2]) | ((unsigned int)f2bf(gx[3])<<16);
      *(uint2*)&EX[eo] = make_uint2(x0,x1);
      gya[ct] = gy;
    }
    wave_lgkm();                       // gx writes done (wave-private rows)

    // read own-wave gx linear quads into regs
    uint2 gxl0 = *(const uint2*)&EX[(r0 + 0 + lk)*EXPU + lr*4];
    uint2 gxl1 = *(const uint2*)&EX[(r0 + 4 + lk)*EXPU + lr*4];
    uint2 gxl2 = *(const uint2*)&EX[(r0 + 8 + lk)*EXPU + lr*4];
    uint2 gxl3 = *(const uint2*)&EX[(r0 +12 + lk)*EXPU + lr*4];
    wave_lgkm();                       // gx reads done before overwrite

    // publish gy into the same EX rows
    #pragma unroll
    for(int ct=0; ct<4; ct++){
      int eo = (r0+lr)*EXPU + (ct*4+lk)*4;
      unsigned int y0 = (unsigned int)f2bf(gya[ct][0]) | ((unsigned int)f2bf(gya[ct][1])<<16);
      unsigned int y1 = (unsigned int)f2bf(gya[ct][2]) | ((unsigned int)f2bf(gya[ct][3])<<16);
      *(uint2*)&EX[eo] = make_uint2(y0,y1);
    }
    wave_lgkm();                       // gy published (wave-local)

    // ---- PIN the hoisted global loads -------------------------------------
    pin4(pm0); pin4(pm1); pin4(pm2); pin4(pm3);
    pin4(sx0); pin4(sx1); pin4(sx2); pin4(sx3);
    pin4(sy0); pin4(sy1); pin4(sy2); pin4(sy3);

    // ---- update phase: wave-local; NT stores stream past L2 ---------------
    float An = Atab[d*16 + n];
    const float4* Bv  = (const float4*)(Bvalw + ((size_t)b*16 + n)*HW_);
    const float4* Cv  = (const float4*)(Cvalw + ((size_t)b*16 + n)*HW_);
    float* so = out_s + sbase + (size_t)n*HW_;
    float4* so0 = (float4*)so;
    float4* so1 = (float4*)(so + PL);
    float4* so2 = (float4*)(so + 2*PL);

    #pragma unroll
    for(int k=0; k<4; k++){
      int g = gA + 64*k;
      float4 B4  = Bv[g];
      float4 C4  = Cv[g];
      // own-wave EX row (now holds gy): r0 + 4k + lk, col quad lr
      int eo = (r0 + 4*k + lk)*EXPU + lr*4;
      uint2 uy = *(const uint2*)&EX[eo];
      uint2 ux = (k==0)?gxl0:(k==1)?gxl1:(k==2)?gxl2:gxl3;
      float4 m04 = (k==0)?pm0:(k==1)?pm1:(k==2)?pm2:pm3;
      float4 mx4 = (k==0)?sx0:(k==1)?sx1:(k==2)?sx2:sx3;
      float4 my4 = (k==0)?sy0:(k==1)?sy1:(k==2)?sy2:sy3;
      float4 u4  = (k==0)?uq0:(k==1)?uq1:(k==2)?uq2:uq3;
      float4 dv_ = (k==0)?dq0:(k==1)?dq1:(k==2)?dq2:dq3;
      float4 ab, m0n, mxn, myn;
      ab.x = __expf(dv_.x*An);
      ab.y = __expf(dv_.y*An);
      ab.z = __expf(dv_.z*An);
      ab.w = __expf(dv_.w*An);
      m0n.x = ab.x*m04.x + dv_.x*B4.x*u4.x;
      m0n.y = ab.y*m04.y + dv_.y*B4.y*u4.y;
      m0n.z = ab.z*m04.z + dv_.z*B4.z*u4.z;
      m0n.w = ab.w*m04.w + dv_.w*B4.w*u4.w;
      mxn.x = ab.x*(mx4.x - bf2f(ux.x));
      mxn.y = ab.y*(mx4.y - bf2f(ux.x>>16));
      mxn.z = ab.z*(mx4.z - bf2f(ux.y));
      mxn.w = ab.w*(mx4.w - bf2f(ux.y>>16));
      myn.x = ab.x*(my4.x - bf2f(uy.x));
      myn.y = ab.y*(my4.y - bf2f(uy.x>>16));
      myn.z = ab.z*(my4.z - bf2f(uy.y));
      myn.w = ab.w*(my4.w - bf2f(uy.y>>16));
      if(k==0){ yq0.x += m0n.x*C4.x; yq0.y += m0n.y*C4.y; yq0.z += m0n.z*C4.z; yq0.w += m0n.w*C4.w; }
      if(k==1){ yq1.x += m0n.x*C4.x; yq1.y += m0n.y*C4.y; yq1.z += m0n.z*C4.z; yq1.w += m0n.w*C4.w; }
      if(k==2){ yq2.x += m0n.x*C4.x; yq2.y += m0n.y*C4.y; yq2.z += m0n.z*C4.z; yq2.w += m0n.w*C4.w; }
      if(k==3){ yq3.x += m0n.x*C4.x; yq3.y += m0n.y*C4.y; yq3.z += m0n.z*C4.z; yq3.w += m0n.w*C4.w; }
      nt_store4(m0n, &so0[g]);
      nt_store4(mxn, &so1[g]);
      nt_store4(myn, &so2[g]);
    }
    bar_lgkm();                        // block barrier (Ms66/EX protection)
  }

  // ---- y atomics: linear, wave-contiguous; even/odd nq2 -> separate buffer -
  float* yb = ((nq2 & 1) ? ybuf2 : ybuf) + bd*HW_;
  #pragma unroll
  for(int k=0; k<4; k++){
    int p = 4*(gA + 64*k);
    float4 yv = (k==0)?yq0:(k==1)?yq1:(k==2)?yq2:yq3;
    atomicAdd(&yb[p+0], yv.x);
    atomicAdd(&yb[p+1], yv.y);
    atomicAdd(&yb[p+2], yv.z);
    atomicAdd(&yb[p+3], yv.w);
  }
}

// ---------------- y epilogue: y = ybuf + ybuf2 + u*D_param ------------------
__global__ void k_y(const float* __restrict__ ybuf,
                    const float* __restrict__ ybuf2,
                    const float* __restrict__ u_t,
                    const float* __restrict__ Dp,
                    float* __restrict__ out_y){
  int i = blockIdx.x*blockDim.x + threadIdx.x;   // 0..262143 float4s (1024 blk)
  int d = (i>>10)&63;
  float Dv = Dp[d];
  float4 uv = ((const float4*)u_t)[i];
  float4 ya = ((const float4*)ybuf)[i];
  float4 yb = ((const float4*)ybuf2)[i];
  v4f o;
  o[0] = ya.x + yb.x + uv.x*Dv;
  o[1] = ya.y + yb.y + uv.y*Dv;
  o[2] = ya.z + yb.z + uv.z*Dv;
  o[3] = ya.w + yb.w + uv.w*Dv;
  __builtin_nontemporal_store(o, (v4f*)&((float4*)out_y)[i]);
}

extern "C" void kernel_launch(void* const* d_in, const int* in_sizes, int n_in,
                              void* d_out, int out_size, void* d_ws, size_t ws_size,
                              hipStream_t stream){
  const float* u_t    = (const float*)d_in[0];
  const float* s_prev = (const float*)d_in[1];
  const float* gamma  = (const float*)d_in[2];
  const float* beta   = (const float*)d_in[3];
  const float* w_d    = (const float*)d_in[4];
  const float* b_d    = (const float*)d_in[5];
  const float* w_B    = (const float*)d_in[6];
  const float* w_C    = (const float*)d_in[7];
  const float* logA   = (const float*)d_in[8];
  const float* Dp     = (const float*)d_in[9];
  const float* dtp    = (const float*)d_in[10];

  char* ws = (char*)d_ws;
  unsigned short* D2w  = (unsigned short*)(ws + OFF_D2);
  float* Atab          = (float*)(ws + OFF_ATAB);
  float* meanw         = (float*)(ws + OFF_MEAN);
  float* rstdw         = (float*)(ws + OFF_RSTD);
  unsigned short* W9   = (unsigned short*)(ws + OFF_W9);
  unsigned short* unT  = (unsigned short*)(ws + OFF_UNT);
  float* deltaw        = (float*)(ws + OFF_DELTA);
  float* Bvalw         = (float*)(ws + OFF_BVAL);
  float* Cvalw         = (float*)(ws + OFF_CVAL);
  float* ybuf          = (float*)(ws + OFF_YBUF);
  float* ybuf2         = (float*)(ws + OFF_YBUF2);

  float* out_y = (float*)d_out;
  float* out_s = out_y + 1048576;

  hipMemsetAsync(ws + OFF_YBUF, 0, 8u*1048576u, stream);   // both y partials
  k_init   <<<20, 256, 0, stream>>>(logA, D2w, Atab);
  k_wrepack<<<24, 256, 0, stream>>>(w_d, w_B, w_C, W9);
  k_gnstats<<<16, 1024, 0, stream>>>(u_t, meanw, rstdw);
  k_unT    <<<256, 256, 0, stream>>>(u_t, meanw, rstdw, gamma, beta, unT);
  k_conv   <<<256, 256, 0, stream>>>(unT, W9, b_d, dtp, deltaw, Bvalw, Cvalw);
  k_main   <<<2048, 256, 0, stream>>>(u_t, s_prev, D2w, Atab, deltaw, Bvalw, Cvalw, ybuf, ybuf2, out_s);
  k_y      <<<1024, 256, 0, stream>>>(ybuf, ybuf2, u_t, Dp, out_y);
}

// Round 18
// 153.773 us; speedup vs baseline: 1.2255x; 1.2255x over previous
//
#include <hip/hip_runtime.h>
#include <hip/hip_bf16.h>

#define B_ 4
#define D_ 64
#define N_ 16
#define HW_ 4096

#define LDSA 72
#define LDSB 66
#define EXPU 68   // EX pitch in u16 (136 B rows)

// workspace offsets (bytes)
#define OFF_D2    0u
#define OFF_ATAB  8192u
#define OFF_MEAN  12288u
#define OFF_RSTD  12352u
#define OFF_W9    16384u
#define OFF_UNT   131072u
#define OFF_DELTA 2228224u
#define OFF_BVAL  6422528u
#define OFF_CVAL  7471104u
#define OFF_YBUF  8519680u

typedef __bf16 v8bf __attribute__((ext_vector_type(8)));
typedef float  v4f  __attribute__((ext_vector_type(4)));

__device__ __forceinline__ unsigned short f2bf(float f){
  __hip_bfloat16 h = __float2bfloat16(f);
  return *reinterpret_cast<unsigned short*>(&h);
}
__device__ __forceinline__ float bf2f(unsigned int u){
  union{unsigned int i; float f;} c; c.i = (u & 0xffffu)<<16; return c.f;
}
__device__ __forceinline__ v8bf ld8bf(const unsigned short* p){
  union{uint4 u; v8bf v;} c; c.u = *(const uint4*)p; return c.v;
}
// non-temporal float4 store via clang ext-vector type
__device__ __forceinline__ void nt_store4(float4 v, float4* p){
  v4f w = {v.x, v.y, v.z, v.w};
  __builtin_nontemporal_store(w, (v4f*)p);
}

// force a float4 to be materialized in VGPRs at this program point
__device__ __forceinline__ void pin4(const float4& v){
  asm volatile("" :: "v"(v.x), "v"(v.y), "v"(v.z), "v"(v.w));
}

// LDS-only barrier: orders cross-thread LDS, leaves global ops in flight
__device__ __forceinline__ void bar_lgkm(){
  asm volatile("s_waitcnt lgkmcnt(0)" ::: "memory");
  __builtin_amdgcn_s_barrier();
  __builtin_amdgcn_sched_barrier(0);
}

// wave-local LDS publish: wait own LDS ops, no block barrier
__device__ __forceinline__ void wave_lgkm(){
  asm volatile("s_waitcnt lgkmcnt(0)" ::: "memory");
  __builtin_amdgcn_sched_barrier(0);
}

// ---------------- init: spectral-derivative table + A = -exp(logA) ----------
__global__ void k_init(const float* __restrict__ logA,
                       unsigned short* __restrict__ D2w, float* __restrict__ Atab){
  int g = blockIdx.x*256 + threadIdx.x;
  if(g < 4096){
    int r = g>>6, m = g&63;
    int p = (r - m) & 63;
    float s = 0.f;
    for(int k=1;k<32;k++) s += (float)k * sinf(0.09817477042468103f * (float)(k*p));
    D2w[g] = f2bf(-0.0030679615757712823f * s);
  } else if(g < 5120){
    int idx = g - 4096;
    Atab[idx] = -__expf(logA[idx]);
  }
}

// ---------------- repack conv weights to [tap][co(96)][ci(64)] bf16 ---------
__global__ void k_wrepack(const float* __restrict__ wd,
                          const float* __restrict__ wB,
                          const float* __restrict__ wC,
                          unsigned short* __restrict__ W9){
  int idx = blockIdx.x*256 + threadIdx.x;   // 0..6143
  if(idx >= 96*64) return;
  int co = idx>>6, ci = idx&63;
  const float* src;
  if(co < 64)      src = wd + ((size_t)co*64 + ci)*9;
  else if(co < 80) src = wB + ((size_t)(co-64)*64 + ci)*9;
  else             src = wC + ((size_t)(co-80)*64 + ci)*9;
  for(int tap=0; tap<9; tap++)
    W9[((size_t)tap*96 + co)*64 + ci] = f2bf(src[tap]);
}

// ---------------- GroupNorm statistics (16 groups of 65536 elems) -----------
__global__ void k_gnstats(const float* __restrict__ u,
                          float* __restrict__ meanw, float* __restrict__ rstdw){
  int bg = blockIdx.x;                       // 0..15  (b*4+g), group contiguous
  const float* base = u + (size_t)bg*65536;
  int t = threadIdx.x;                       // 0..1023
  float s=0.f, s2=0.f;
  for(int j=0;j<16;j++){
    float4 v = ((const float4*)base)[t + 1024*j];
    s  += v.x+v.y+v.z+v.w;
    s2 += v.x*v.x+v.y*v.y+v.z*v.z+v.w*v.w;
  }
  for(int o=32;o>0;o>>=1){ s += __shfl_down(s,o); s2 += __shfl_down(s2,o); }
  __shared__ float ls[16], ls2[16];
  int wv = t>>6;
  if((t&63)==0){ ls[wv]=s; ls2[wv]=s2; }
  __syncthreads();
  if(t==0){
    float S=0.f,S2=0.f;
    for(int i=0;i<16;i++){ S+=ls[i]; S2+=ls2[i]; }
    float mu = S/65536.f;
    float var = S2/65536.f - mu*mu;
    meanw[bg]=mu; rstdw[bg]=rsqrtf(var+1e-5f);
  }
}

// ---------------- apply GN + transpose to unT[b][pixel][ci] (bf16) ----------
__global__ __launch_bounds__(256) void k_unT(
    const float* __restrict__ u_t,
    const float* __restrict__ meanw, const float* __restrict__ rstdw,
    const float* __restrict__ gamma, const float* __restrict__ beta,
    unsigned short* __restrict__ unT){
  __shared__ unsigned short T[64*LDSA];
  int bid = blockIdx.x;
  int b = bid>>6, h = bid&63;
  int t = threadIdx.x;
  int w = t&63, cg = t>>6;
  #pragma unroll
  for(int i=0;i<16;i++){
    int c = cg*16 + i;
    float x = u_t[(((size_t)b*64 + c)*64 + h)*64 + w];
    int g = c>>4;
    float v = (x - meanw[b*4+g])*rstdw[b*4+g]*gamma[c] + beta[c];
    T[w*LDSA + c] = f2bf(v);
  }
  __syncthreads();
  int w2 = t>>2, cq = t&3;
  uint4 v0 = *(uint4*)&T[w2*LDSA + cq*16];
  uint4 v1 = *(uint4*)&T[w2*LDSA + cq*16 + 8];
  uint4* dst = (uint4*)(unT + ((size_t)b*HW_ + h*64 + w2)*64 + cq*16);
  dst[0] = v0; dst[1] = v1;
}

// ---------------- conv as 9 shifted GEMMs via MFMA --------------------------
__global__ __launch_bounds__(256) void k_conv(
    const unsigned short* __restrict__ unT,
    const unsigned short* __restrict__ W9,
    const float* __restrict__ b_d,
    const float* __restrict__ dtp,
    float* __restrict__ deltaw, float* __restrict__ Bvalw, float* __restrict__ Cvalw){
  int bid = blockIdx.x;
  int b = bid>>6, h = bid&63;
  int t = threadIdx.x;
  int wv = t>>6, l = t&63;
  int lr = l&15, lk = l>>4;
  v4f acc[6];
  #pragma unroll
  for(int i=0;i<6;i++) acc[i] = (v4f){0.f,0.f,0.f,0.f};
  int wpix = wv*16 + lr;
  #pragma unroll
  for(int tap=0; tap<9; tap++){
    int dy = tap/3 - 1, dx = tap - (tap/3)*3 - 1;
    int hh = (h+dy)&63;
    int ww = (wpix+dx)&63;
    const unsigned short* bp = unT + ((size_t)b*HW_ + hh*64 + ww)*64;
    const unsigned short* ap = W9 + (size_t)tap*96*64;
    #pragma unroll
    for(int ks=0; ks<2; ks++){
      int k0 = ks*32 + lk*8;
      v8bf bfrag = ld8bf(bp + k0);
      #pragma unroll
      for(int mt=0; mt<6; mt++){
        v8bf afrag = ld8bf(ap + (mt*16+lr)*64 + k0);
        acc[mt] = __builtin_amdgcn_mfma_f32_16x16x32_bf16(afrag, bfrag, acc[mt], 0,0,0);
      }
    }
  }
  float dt = dtp[0];
  int p = h*64 + wpix;
  #pragma unroll
  for(int mt=0; mt<6; mt++){
    #pragma unroll
    for(int r=0;r<4;r++){
      int co = mt*16 + lk*4 + r;
      float v = acc[mt][r];
      if(co < 64){
        float x = v + b_d[co] + dt;
        float sp = (x > 15.f) ? x : log1pf(__expf(x));
        sp = fminf(fmaxf(sp, 1e-4f), 5.f);
        deltaw[((size_t)b*64 + co)*HW_ + p] = sp;
      } else if(co < 80){
        Bvalw[((size_t)b*16 + (co-64))*HW_ + p] = v;
      } else {
        Cvalw[((size_t)b*16 + (co-80))*HW_ + p] = v;
      }
    }
  }
}

// ---------------- fused spectral-grad + state update ------------------------
// v18 = R16 (wave-local exchange + NT out_s, grid 1024, best 158.8us) with
// __launch_bounds__ 4 -> 2. THE 64-VGPR MYSTERY WAS SELF-INFLICTED:
// (256,4) = min 4 waves/EU caps the allocator at 2048/4 = 64 VGPR, which is
// why every register-residency attempt (R8 hoist, R10 D2-regs, R13 pins)
// silently sank. At 128 VGPR the HW still fits 16 waves/CU = 4 blocks
// (VGPR-limited at exactly today's residency; LDS would allow 6) -> doubling
// the register budget is free. Pins + hoisted pm/sx/sy/u/delta can now
// genuinely materialize; update phase runs from registers.
__global__ __launch_bounds__(256, 2) void k_main(
    const float* __restrict__ u_t,
    const float* __restrict__ s_prev,
    const unsigned short* __restrict__ D2w,
    const float* __restrict__ Atab,
    const float* __restrict__ deltaw,
    const float* __restrict__ Bvalw,
    const float* __restrict__ Cvalw,
    float* __restrict__ ybuf,
    float* __restrict__ out_s){
  __shared__ __align__(16) unsigned short Ms66[64*LDSB];   // 8448 B
  __shared__ __align__(16) unsigned short D2s [64*LDSB];   // 8448 B
  __shared__ __align__(16) unsigned short EX  [64*EXPU];   // 8704 B

  int bid = blockIdx.x;                 // bid = nq*256 + (d*4+b)
  int pair = bid & 255;
  int b = pair & 3, d = pair >> 2;
  int nq = bid >> 8;
  int t = threadIdx.x;
  int wv = t>>6, l = t&63;
  int lr = l & 15, lk = l >> 4;
  int r0 = wv*16;
  int gA = wv*256 + l;                  // granule base; granule k = gA + 64k

  size_t bd = (size_t)b*64 + d;
  const size_t PL = (size_t)D_*N_*HW_;
  size_t sbase = (size_t)b*3*PL + (size_t)d*N_*HW_;
  int n0 = nq*4;

  const float* m0base = s_prev + sbase;
  const float* mxbase = s_prev + sbase + PL;
  const float* mybase = s_prev + sbase + 2*PL;

  // ---- D2 staging (pitch 66) + u/delta block-resident (remapped granules) -
  uint4 d2v0 = ((const uint4*)D2w)[t];
  uint4 d2v1 = ((const uint4*)D2w)[t+256];
  { int r = t>>3, cb = t&7;            *(uint4*)&D2s[r*LDSB + cb*8] = d2v0; }
  { int c2 = t+256; int r = c2>>3, cb = c2&7; *(uint4*)&D2s[r*LDSB + cb*8] = d2v1; }
  const float4* uv4 = (const float4*)(u_t + bd*HW_);
  const float4* dv4 = (const float4*)(deltaw + bd*HW_);
  float4 uq0 = uv4[gA], uq1 = uv4[gA+64], uq2 = uv4[gA+128], uq3 = uv4[gA+192];
  float4 dq0 = dv4[gA], dq1 = dv4[gA+64], dq2 = dv4[gA+128], dq3 = dv4[gA+192];

  float4 yq0 = make_float4(0.f,0.f,0.f,0.f);
  float4 yq1 = yq0, yq2 = yq0, yq3 = yq0;

  for(int ni=0; ni<4; ni++){
    int n = n0 + ni;
    // ---- read burst (top of ni): m0 first, then mx/my (remapped) ----------
    const float4* m0v = (const float4*)(m0base + (size_t)n*HW_);
    float4 pm0 = m0v[gA], pm1 = m0v[gA+64], pm2 = m0v[gA+128], pm3 = m0v[gA+192];
    const float4* mxv = (const float4*)(mxbase + (size_t)n*HW_);
    const float4* myv = (const float4*)(mybase + (size_t)n*HW_);
    float4 sx0 = mxv[gA], sx1 = mxv[gA+64], sx2 = mxv[gA+128], sx3 = mxv[gA+192];
    float4 sy0 = myv[gA], sy1 = myv[gA+64], sy2 = myv[gA+128], sy3 = myv[gA+192];

    // ---- stage m0 (fp32->bf16) into Ms66 (single copy) --------------------
    // granule k: row = r0 + 4k + lk, col quad = lr
    #pragma unroll
    for(int j=0;j<4;j++){
      float4 v = (j==0)?pm0:(j==1)?pm1:(j==2)?pm2:pm3;
      int row = r0 + 4*j + lk;
      unsigned int lo = (unsigned int)f2bf(v.x) | ((unsigned int)f2bf(v.y)<<16);
      unsigned int hi = (unsigned int)f2bf(v.z) | ((unsigned int)f2bf(v.w)<<16);
      unsigned int* d66 = (unsigned int*)&Ms66[row*LDSB + lr*4];
      d66[0]=lo; d66[1]=hi;
    }
    bar_lgkm();                        // publish M; mx/my keep flying

    // ---- MFMA phase: gx -> EX immediately; gy held in regs ----------------
    v4f gya[4];
    #pragma unroll
    for(int ct=0; ct<4; ct++){
      v4f gx = {0.f,0.f,0.f,0.f}, gy = {0.f,0.f,0.f,0.f};
      #pragma unroll
      for(int ks=0; ks<2; ks++){
        int k0 = ks*32 + lk*8;
        // Gx^T = D2 * M^T : row-contiguous reads from pitch-66
        v8bf a_gx = ld8bf(&D2s[(ct*16+lr)*LDSB + k0]);
        v8bf b_gx = ld8bf(&Ms66[(r0+lr)*LDSB + k0]);
        gx = __builtin_amdgcn_mfma_f32_16x16x32_bf16(a_gx, b_gx, gx, 0,0,0);
        // Gy^T = M^T * D2^T : conflict-free column gather (66-pitch design)
        union { unsigned short s[8]; v8bf v; } ag;
        #pragma unroll
        for(int i=0;i<8;i++) ag.s[i] = Ms66[(k0+i)*LDSB + ct*16 + lr];
        v8bf b_gy = ld8bf(&D2s[(r0+lr)*LDSB + k0]);
        gy = __builtin_amdgcn_mfma_f32_16x16x32_bf16(ag.v, b_gy, gy, 0,0,0);
      }
      // gx fragment (row r0+lr, cols ct*16+lk*4+{0..3}) -> bf16-packed EX
      int eo = (r0+lr)*EXPU + (ct*4+lk)*4;
      unsigned int x0 = (unsigned int)f2bf(gx[0]) | ((unsigned int)f2bf(gx[1])<<16);
      unsigned int x1 = (unsigned int)f2bf(gx[2]) | ((unsigned int)f2bf(gx[3])<<16);
      *(uint2*)&EX[eo] = make_uint2(x0,x1);
      gya[ct] = gy;
    }
    wave_lgkm();                       // gx writes done (wave-private rows)

    // read own-wave gx linear quads into regs
    uint2 gxl0 = *(const uint2*)&EX[(r0 + 0 + lk)*EXPU + lr*4];
    uint2 gxl1 = *(const uint2*)&EX[(r0 + 4 + lk)*EXPU + lr*4];
    uint2 gxl2 = *(const uint2*)&EX[(r0 + 8 + lk)*EXPU + lr*4];
    uint2 gxl3 = *(const uint2*)&EX[(r0 +12 + lk)*EXPU + lr*4];
    wave_lgkm();                       // gx reads done before overwrite

    // publish gy into the same EX rows
    #pragma unroll
    for(int ct=0; ct<4; ct++){
      int eo = (r0+lr)*EXPU + (ct*4+lk)*4;
      unsigned int y0 = (unsigned int)f2bf(gya[ct][0]) | ((unsigned int)f2bf(gya[ct][1])<<16);
      unsigned int y1 = (unsigned int)f2bf(gya[ct][2]) | ((unsigned int)f2bf(gya[ct][3])<<16);
      *(uint2*)&EX[eo] = make_uint2(y0,y1);
    }
    wave_lgkm();                       // gy published (wave-local)

    // ---- PIN the hoisted global loads (128-VGPR budget: they can now stay) -
    pin4(pm0); pin4(pm1); pin4(pm2); pin4(pm3);
    pin4(sx0); pin4(sx1); pin4(sx2); pin4(sx3);
    pin4(sy0); pin4(sy1); pin4(sy2); pin4(sy3);

    // ---- update phase: wave-local; NT stores stream past L2 ---------------
    float An = Atab[d*16 + n];
    const float4* Bv  = (const float4*)(Bvalw + ((size_t)b*16 + n)*HW_);
    const float4* Cv  = (const float4*)(Cvalw + ((size_t)b*16 + n)*HW_);
    float* so = out_s + sbase + (size_t)n*HW_;
    float4* so0 = (float4*)so;
    float4* so1 = (float4*)(so + PL);
    float4* so2 = (float4*)(so + 2*PL);

    #pragma unroll
    for(int k=0; k<4; k++){
      int g = gA + 64*k;
      float4 B4  = Bv[g];
      float4 C4  = Cv[g];
      // own-wave EX row (now holds gy): r0 + 4k + lk, col quad lr
      int eo = (r0 + 4*k + lk)*EXPU + lr*4;
      uint2 uy = *(const uint2*)&EX[eo];
      uint2 ux = (k==0)?gxl0:(k==1)?gxl1:(k==2)?gxl2:gxl3;
      float4 m04 = (k==0)?pm0:(k==1)?pm1:(k==2)?pm2:pm3;
      float4 mx4 = (k==0)?sx0:(k==1)?sx1:(k==2)?sx2:sx3;
      float4 my4 = (k==0)?sy0:(k==1)?sy1:(k==2)?sy2:sy3;
      float4 u4  = (k==0)?uq0:(k==1)?uq1:(k==2)?uq2:uq3;
      float4 dv_ = (k==0)?dq0:(k==1)?dq1:(k==2)?dq2:dq3;
      float4 ab, m0n, mxn, myn;
      ab.x = __expf(dv_.x*An);
      ab.y = __expf(dv_.y*An);
      ab.z = __expf(dv_.z*An);
      ab.w = __expf(dv_.w*An);
      m0n.x = ab.x*m04.x + dv_.x*B4.x*u4.x;
      m0n.y = ab.y*m04.y + dv_.y*B4.y*u4.y;
      m0n.z = ab.z*m04.z + dv_.z*B4.z*u4.z;
      m0n.w = ab.w*m04.w + dv_.w*B4.w*u4.w;
      mxn.x = ab.x*(mx4.x - bf2f(ux.x));
      mxn.y = ab.y*(mx4.y - bf2f(ux.x>>16));
      mxn.z = ab.z*(mx4.z - bf2f(ux.y));
      mxn.w = ab.w*(mx4.w - bf2f(ux.y>>16));
      myn.x = ab.x*(my4.x - bf2f(uy.x));
      myn.y = ab.y*(my4.y - bf2f(uy.x>>16));
      myn.z = ab.z*(my4.z - bf2f(uy.y));
      myn.w = ab.w*(my4.w - bf2f(uy.y>>16));
      if(k==0){ yq0.x += m0n.x*C4.x; yq0.y += m0n.y*C4.y; yq0.z += m0n.z*C4.z; yq0.w += m0n.w*C4.w; }
      if(k==1){ yq1.x += m0n.x*C4.x; yq1.y += m0n.y*C4.y; yq1.z += m0n.z*C4.z; yq1.w += m0n.w*C4.w; }
      if(k==2){ yq2.x += m0n.x*C4.x; yq2.y += m0n.y*C4.y; yq2.z += m0n.z*C4.z; yq2.w += m0n.w*C4.w; }
      if(k==3){ yq3.x += m0n.x*C4.x; yq3.y += m0n.y*C4.y; yq3.z += m0n.z*C4.z; yq3.w += m0n.w*C4.w; }
      nt_store4(m0n, &so0[g]);
      nt_store4(mxn, &so1[g]);
      nt_store4(myn, &so2[g]);
    }
    bar_lgkm();                        // block barrier (Ms66/EX protection)
  }

  // ---- y atomics: linear, wave-contiguous (remapped granules) -------------
  float* yb = ybuf + bd*HW_;
  #pragma unroll
  for(int k=0; k<4; k++){
    int p = 4*(gA + 64*k);
    float4 yv = (k==0)?yq0:(k==1)?yq1:(k==2)?yq2:yq3;
    atomicAdd(&yb[p+0], yv.x);
    atomicAdd(&yb[p+1], yv.y);
    atomicAdd(&yb[p+2], yv.z);
    atomicAdd(&yb[p+3], yv.w);
  }
}

// ---------------- y epilogue: y = ybuf + u*D_param --------------------------
__global__ void k_y(const float* __restrict__ ybuf,
                    const float* __restrict__ u_t,
                    const float* __restrict__ Dp,
                    float* __restrict__ out_y){
  int i = blockIdx.x*blockDim.x + threadIdx.x;   // 0..262143 float4s (1024 blk)
  int d = (i>>10)&63;
  float Dv = Dp[d];
  float4 uv = ((const float4*)u_t)[i];
  float4 yv = ((const float4*)ybuf)[i];
  v4f o;
  o[0] = yv.x + uv.x*Dv;
  o[1] = yv.y + uv.y*Dv;
  o[2] = yv.z + uv.z*Dv;
  o[3] = yv.w + uv.w*Dv;
  __builtin_nontemporal_store(o, (v4f*)&((float4*)out_y)[i]);
}

extern "C" void kernel_launch(void* const* d_in, const int* in_sizes, int n_in,
                              void* d_out, int out_size, void* d_ws, size_t ws_size,
                              hipStream_t stream){
  const float* u_t    = (const float*)d_in[0];
  const float* s_prev = (const float*)d_in[1];
  const float* gamma  = (const float*)d_in[2];
  const float* beta   = (const float*)d_in[3];
  const float* w_d    = (const float*)d_in[4];
  const float* b_d    = (const float*)d_in[5];
  const float* w_B    = (const float*)d_in[6];
  const float* w_C    = (const float*)d_in[7];
  const float* logA   = (const float*)d_in[8];
  const float* Dp     = (const float*)d_in[9];
  const float* dtp    = (const float*)d_in[10];

  char* ws = (char*)d_ws;
  unsigned short* D2w  = (unsigned short*)(ws + OFF_D2);
  float* Atab          = (float*)(ws + OFF_ATAB);
  float* meanw         = (float*)(ws + OFF_MEAN);
  float* rstdw         = (float*)(ws + OFF_RSTD);
  unsigned short* W9   = (unsigned short*)(ws + OFF_W9);
  unsigned short* unT  = (unsigned short*)(ws + OFF_UNT);
  float* deltaw        = (float*)(ws + OFF_DELTA);
  float* Bvalw         = (float*)(ws + OFF_BVAL);
  float* Cvalw         = (float*)(ws + OFF_CVAL);
  float* ybuf          = (float*)(ws + OFF_YBUF);

  float* out_y = (float*)d_out;
  float* out_s = out_y + 1048576;

  hipMemsetAsync(ws + OFF_YBUF, 0, 4u*1048576u, stream);
  k_init   <<<20, 256, 0, stream>>>(logA, D2w, Atab);
  k_wrepack<<<24, 256, 0, stream>>>(w_d, w_B, w_C, W9);
  k_gnstats<<<16, 1024, 0, stream>>>(u_t, meanw, rstdw);
  k_unT    <<<256, 256, 0, stream>>>(u_t, meanw, rstdw, gamma, beta, unT);
  k_conv   <<<256, 256, 0, stream>>>(unT, W9, b_d, dtp, deltaw, Bvalw, Cvalw);
  k_main   <<<1024, 256, 0, stream>>>(u_t, s_prev, D2w, Atab, deltaw, Bvalw, Cvalw, ybuf, out_s);
  k_y      <<<1024, 256, 0, stream>>>(ybuf, u_t, Dp, out_y);
}